// Round 10
// baseline (199.638 us; speedup 1.0000x reference)
//
#include <hip/hip_runtime.h>
#include <hip/hip_bf16.h>
#include <math.h>

#define B_ 2
#define S_ 2048
#define E_ 1024
#define H_ 16
#define D_ 64
#define M_ (B_*S_)
#define PT 32

typedef short bf16x8 __attribute__((ext_vector_type(8)));
typedef float f32x4 __attribute__((ext_vector_type(4)));
typedef unsigned short u16x4 __attribute__((ext_vector_type(4)));

#define SCLQ 0.18033688011112042f  // log2(e)/8 folded into Q

__device__ __forceinline__ unsigned short f2bf(float f) {
    unsigned int u = __builtin_bit_cast(unsigned int, f);
    u += 0x7FFFu + ((u >> 16) & 1u);
    return (unsigned short)(u >> 16);
}
__device__ __forceinline__ unsigned int pk2bf(float a, float b) {
    __hip_bfloat162 h = __float22bfloat162_rn(make_float2(a, b));
    unsigned int u;
    __builtin_memcpy(&u, &h, 4);
    return u;
}
__device__ __forceinline__ f32x4 mfma16(bf16x8 a, bf16x8 b, f32x4 c) {
    return __builtin_amdgcn_mfma_f32_16x16x32_bf16(a, b, c, 0, 0, 0);
}
__device__ __forceinline__ bf16x8 cvt8(const float* p) {
    f32x4 lo = *(const f32x4*)p;
    f32x4 hi = *(const f32x4*)(p + 4);
    unsigned int pk[4];
    pk[0] = pk2bf(lo[0], lo[1]);
    pk[1] = pk2bf(lo[2], lo[3]);
    pk[2] = pk2bf(hi[0], hi[1]);
    pk[3] = pk2bf(hi[2], hi[3]);
    bf16x8 r;
    __builtin_memcpy(&r, pk, 16);
    return r;
}
__device__ __forceinline__ void g2l16(const unsigned short* g, unsigned short* l) {
    __builtin_amdgcn_global_load_lds(
        (const __attribute__((address_space(1))) unsigned int*)(const void*)g,
        (__attribute__((address_space(3))) unsigned int*)(void*)l,
        16, 0, 0);
}

// ---------------- Kernel 0: f32->bf16 conversion + RoPE tables --------------
__global__ __launch_bounds__(256) void cvt_kernel(
    const float* __restrict__ X,  const float* __restrict__ Wq,
    const float* __restrict__ Wk, const float* __restrict__ Wv,
    const float* __restrict__ Wo,
    unsigned short* __restrict__ Xb, unsigned short* __restrict__ Wb,
    float* __restrict__ tab)   // [cs 32*2048][sn 32*2048]
{
    const int y = blockIdx.y;
    if (y == 5) {
        // RoPE tables: tab[f*2048+s] = cos(angle), tab[65536 + f*2048+s] = sin
        unsigned int i = blockIdx.x * 256 + threadIdx.x;
        if (i < 32 * 2048) {
            int f = i >> 11, s = i & 2047;
            const float C = -0.41524101186091903f;     // -log2(10000)/32
            const float INV2PI = 0.15915494309189535f;
            float inv_rev = exp2f(C * (float)f) * INV2PI;
            float rev = (float)s * inv_rev;
            float fr = rev - rintf(rev);
            tab[i]           = __builtin_amdgcn_cosf(fr);
            tab[65536 + i]   = __builtin_amdgcn_sinf(fr);
        }
        return;
    }
    const float* src = (y == 0) ? X : (y == 1) ? Wq : (y == 2) ? Wk : (y == 3) ? Wv : Wo;
    unsigned short* dst = (y == 0) ? Xb : Wb + (size_t)(y - 1) * (E_ * E_);
    const size_t n = (y == 0) ? (size_t)M_ * E_ : (size_t)E_ * E_;
    size_t i = ((size_t)blockIdx.x * 256 + threadIdx.x) * 8;
    if (i < n) *(bf16x8*)(dst + i) = cvt8(src + i);
}

// ---------------- Kernel 1: QKV proj + RoPE (bf16, g2l16, table trig) -------
// R8-exact version (best measured). R6 BK=64 / R9 dbuf both measured null:
// staging latency is already covered by 4-block/CU wave overlap (m99/m100).
__global__ __launch_bounds__(256, 4) void qkv_rope_bf(
    const unsigned short* __restrict__ Xb, const unsigned short* __restrict__ Wb,
    const float* __restrict__ bq, const float* __restrict__ bk,
    const float* __restrict__ bv, const float* __restrict__ tab,
    unsigned short* __restrict__ Qo, unsigned short* __restrict__ Ko,
    unsigned short* __restrict__ Vo)
{
    __shared__ __align__(16) unsigned char lds_raw[128 * 132 * 2];
    unsigned short* As = (unsigned short*)lds_raw;
    unsigned short* Bs = (unsigned short*)(lds_raw + 8192);
    unsigned short* Cs = (unsigned short*)lds_raw;

    const int t = threadIdx.x;
    const int w = t >> 6, lane = t & 63, quad = lane >> 4, l16 = lane & 15;
    const int wr = (w >> 1) * 64, wc = (w & 1) * 64;
    const int n0 = blockIdx.x * 128, m0 = blockIdx.y * 128;
    const int z = blockIdx.z;
    const unsigned short* W = Wb + (size_t)z * (E_ * E_);
    const float* bias = (z == 0) ? bq : (z == 1) ? bk : bv;

    const int r4 = t >> 2, c8 = (t & 3) * 8;
    const unsigned short* Ag = Xb + (size_t)(m0 + r4) * E_ + c8;
    const unsigned short* Bg = W  + (size_t)(n0 + r4) * E_ + c8;

    f32x4 zero = {0.f, 0.f, 0.f, 0.f};
    f32x4 acc[4][4];
#pragma unroll
    for (int i = 0; i < 4; i++)
#pragma unroll
        for (int j = 0; j < 4; j++) acc[i][j] = zero;

    for (int kt = 0; kt < E_; kt += 32) {
        __syncthreads();
        g2l16(Ag + kt,           &As[t * 8]);
        g2l16(Ag + 64 * E_ + kt, &As[t * 8 + 2048]);
        g2l16(Bg + kt,           &Bs[t * 8]);
        g2l16(Bg + 64 * E_ + kt, &Bs[t * 8 + 2048]);
        __syncthreads();
        bf16x8 af[4], bfr[4];
#pragma unroll
        for (int i = 0; i < 4; i++)
            af[i] = *(const bf16x8*)&As[(wr + i * 16 + l16) * 32 + quad * 8];
#pragma unroll
        for (int j = 0; j < 4; j++)
            bfr[j] = *(const bf16x8*)&Bs[(wc + j * 16 + l16) * 32 + quad * 8];
#pragma unroll
        for (int i = 0; i < 4; i++)
#pragma unroll
            for (int j = 0; j < 4; j++)
                acc[i][j] = mfma16(af[i], bfr[j], acc[i][j]);
    }

    __syncthreads();
    const int seg = quad;
    if (z < 2) {
        const float qscale = (z == 0) ? SCLQ : 1.0f;
#pragma unroll
        for (int j = 0; j < 4; j++) {
            int n_local = wc + j * 16 + l16;
            int n = n0 + n_local;
            int d = n & 63, f = d >> 1;
            float bvv = bias[n];
            float sgn = (d & 1) ? 1.f : -1.f;
            const float* ct = tab + f * 2048;
            const float* st_ = tab + 65536 + f * 2048;
#pragma unroll
            for (int i = 0; i < 4; i++) {
                int mb = wr + i * 16 + quad * 4;
                int sb = (m0 + mb) & (S_ - 1);
                f32x4 cs4 = *(const f32x4*)&ct[sb];
                f32x4 sn4 = *(const f32x4*)&st_[sb];
#pragma unroll
                for (int r = 0; r < 4; r++) {
                    float val = acc[i][j][r] + bvv;
                    float oth = __shfl_xor(val, 1);
                    Cs[(mb + r) * 132 + n_local] =
                        f2bf((val * cs4[r] + sgn * oth * sn4[r]) * qscale);
                }
            }
        }
        __syncthreads();
        unsigned short* Out = (z == 0) ? Qo : Ko;
        const int btok = m0 >> 11;
        const int half = seg & 1;
#pragma unroll
        for (int it = 0; it < 16; it++) {
            int m_local = it * 8 + w * 2 + (seg >> 1);
            int s = (m0 + m_local) & (S_ - 1);
            int h = (n0 + half * 64) >> 6;
            u16x4 v = *(const u16x4*)&Cs[m_local * 132 + half * 64 + l16 * 4];
            *(u16x4*)&Out[(((size_t)btok * H_ + h) * S_ + s) * D_ + l16 * 4] = v;
        }
    } else {
#pragma unroll
        for (int j = 0; j < 4; j++) {
            int n_local = wc + j * 16 + l16;
            float bvv = bias[n0 + n_local];
#pragma unroll
            for (int i = 0; i < 4; i++) {
                int mb = wr + i * 16 + quad * 4;
#pragma unroll
                for (int r = 0; r < 4; r++)
                    Cs[n_local * 132 + mb + r] = f2bf(acc[i][j][r] + bvv);
            }
        }
        __syncthreads();
        const int btok = m0 >> 11;
        const int s0 = m0 & (S_ - 1);
        const int half = seg & 1;
#pragma unroll
        for (int it = 0; it < 16; it++) {
            int n_local = it * 8 + w * 2 + (seg >> 1);
            int n = n0 + n_local;
            int h = n >> 6, d = n & 63;
            u16x4 v = *(const u16x4*)&Cs[n_local * 132 + half * 64 + l16 * 4];
            *(u16x4*)&Vo[(((size_t)btok * H_ + h) * D_ + d) * S_ + s0 + half * 64 + l16 * 4] = v;
        }
    }
}

// ---------------- Kernel 2: attention, 256 thr, 4 blocks/CU -----------------
// R10: QBLK=64, 4 waves, grid (32,32)=1024 blocks -> 4 independent barrier
// groups per CU (R4 lesson: this structure needs multi-block overlap to
// cover barrier drains; 2 groups left ~43% idle issue). LDS cut to 40KB:
//   - K 2-buffer: stage K[i+2] into Ks[i&1]; K[i]'s last read (QK(i), iter
//     i-1) completed before the barrier at top of iter i -> safe.
//   - V 2-buffer staged ONE ahead: stage V[i+1] into Vs[(i+1)&1] while
//     PV(i) reads Vs[i&1] (disjoint). Extra barrier after the loop drains
//     V[NT-1] before the final PV.
//   - Ps stride 64 + 16B-slot XOR swizzle (replaces 72-pad):
//     P[row][col] stored at row*64 + ((col>>3 ^ ((row>>1)&3))<<3) + (col&7).
// Pipeline/setprio/K-V involution/XCD chunking unchanged from R8.
__global__ __launch_bounds__(256, 4) void attn_direct(
    const unsigned short* __restrict__ Q, const unsigned short* __restrict__ K,
    const unsigned short* __restrict__ Vt, unsigned short* __restrict__ ctx)
{
    __shared__ unsigned short Ks[2][64 * 64];
    __shared__ unsigned short Vs[2][64 * 64];
    __shared__ unsigned short Ps[4][16 * 64];
    const int t = threadIdx.x;
    const int w = t >> 6, lane = t & 63, quad = lane >> 4, l16 = lane & 15;

    // XCD swizzle: grid (32,32) = 1024 wgs; chunk = 128 wgs/XCD = 4 heads
    const int wgid = blockIdx.x + (blockIdx.y << 5);
    const int sw = (wgid & 7) * 128 + (wgid >> 3);
    const int bh = sw >> 5;
    const int q0 = (sw & 31) * 64 + w * 16;
    const int NT = S_ / 64;   // 32 k/v tiles

    const unsigned short* Qg = Q + ((size_t)bh * S_ + q0) * D_;
    bf16x8 qf[2];
#pragma unroll
    for (int ks = 0; ks < 2; ks++)
        qf[ks] = *(const bf16x8*)(Qg + (size_t)l16 * 64 + ks * 32 + quad * 8);

    bf16x8 ones;
#pragma unroll
    for (int e = 0; e < 8; e++) ones[e] = (short)0x3F80;

    f32x4 zero = {0.f, 0.f, 0.f, 0.f};
    f32x4 acc_o[4];
    f32x4 acc_l = zero;
#pragma unroll
    for (int j = 0; j < 4; j++) acc_o[j] = zero;

    // staging: 256 threads, thread t covers 64B (4 slots of 16B) of row t>>2
    // in each ksel-half; global source slot pre-swizzled by the involution
    // slot ^= (row>>1)&3 (LDS dest stays linear per g2l16 requirement).
    const int sr = t >> 2;
    const int sc = ((t & 3) ^ ((t >> 3) & 3)) * 8;
    const unsigned short* KgL = K  + (size_t)bh * S_ * D_ + (size_t)sr * 64 + sc;
    const unsigned short* VgL = Vt + (size_t)bh * D_ * S_ + (size_t)sr * S_ + sc;

    // read-side swizzled slot for K/V b128 reads (units of 8 elems = 16B)
    const int sl = (quad ^ ((l16 >> 1) & 3)) * 8;
    // Ps read slots (stride-64 swizzle): constant per lane
    const int ps0 = l16 * 64 + ((quad ^ ((l16 >> 1) & 3)) << 3);
    const int ps1 = l16 * 64 + (((4 + quad) ^ ((l16 >> 1) & 3)) << 3);

    // ---- prologue: stage K0,V0; drain; stage K1; QK(0) -> exp -> Ps ----
#pragma unroll
    for (int k2 = 0; k2 < 2; k2++) {
        g2l16(KgL + k2 * 32, &Ks[0][k2 * 2048 + t * 8]);
        g2l16(VgL + k2 * 32, &Vs[0][k2 * 2048 + t * 8]);
    }
    __syncthreads();
#pragma unroll
    for (int k2 = 0; k2 < 2; k2++)
        g2l16(KgL + 4096 + k2 * 32, &Ks[1][k2 * 2048 + t * 8]);
    {
        f32x4 sc4[4];
#pragma unroll
        for (int j = 0; j < 4; j++) sc4[j] = zero;
#pragma unroll
        for (int ks = 0; ks < 2; ks++)
#pragma unroll
            for (int j = 0; j < 4; j++) {
                bf16x8 kf = *(const bf16x8*)&Ks[0][ks * 2048 + (j * 16 + l16) * 32 + sl];
                sc4[j] = mfma16(qf[ks], kf, sc4[j]);
            }
#pragma unroll
        for (int j = 0; j < 4; j++) {
            int cb = 2 * j + (l16 >> 3);
#pragma unroll
            for (int r = 0; r < 4; r += 2) {
                float pa = __builtin_amdgcn_exp2f(sc4[j][r]);
                float pb = __builtin_amdgcn_exp2f(sc4[j][r + 1]);
                unsigned int u = pk2bf(pa, pb);
                int slot = cb ^ ((quad * 2 + (r >> 1)) & 3);
                int a0 = (quad * 4 + r) * 64 + slot * 8 + (l16 & 7);
                Ps[w][a0]      = (unsigned short)u;
                Ps[w][a0 + 64] = (unsigned short)(u >> 16);
            }
        }
    }

    // ---- main loop: stage K(i+2),V(i+1); QK(i+1) || PV(i); exp -> Ps ----
    for (int i = 0; i < NT - 1; ++i) {
        __syncthreads();          // drains K[i+1] (and V[i] for i=0 via prologue)
        if (i + 2 < NT) {
#pragma unroll
            for (int k2 = 0; k2 < 2; k2++)
                g2l16(KgL + (size_t)(i + 2) * 4096 + k2 * 32,
                      &Ks[i & 1][k2 * 2048 + t * 8]);
        }
#pragma unroll
        for (int k2 = 0; k2 < 2; k2++)
            g2l16(VgL + (i + 1) * 64 + k2 * 32,
                  &Vs[(i + 1) & 1][k2 * 2048 + t * 8]);

        bf16x8 pf0 = *(const bf16x8*)&Ps[w][ps0];
        bf16x8 pf1 = *(const bf16x8*)&Ps[w][ps1];

        __builtin_amdgcn_s_setprio(1);
        // QK(i+1) from Ks[(i+1)&1]
        f32x4 scn[4];
#pragma unroll
        for (int j = 0; j < 4; j++) scn[j] = zero;
#pragma unroll
        for (int ks = 0; ks < 2; ks++)
#pragma unroll
            for (int j = 0; j < 4; j++) {
                bf16x8 kf = *(const bf16x8*)&Ks[(i + 1) & 1][ks * 2048 + (j * 16 + l16) * 32 + sl];
                scn[j] = mfma16(qf[ks], kf, scn[j]);
            }
        // PV(i) from Vs[i&1]
#pragma unroll
        for (int jd = 0; jd < 4; jd++) {
            bf16x8 vf = *(const bf16x8*)&Vs[i & 1][(jd * 16 + l16) * 32 + sl];
            acc_o[jd] = mfma16(pf0, vf, acc_o[jd]);
        }
        acc_l = mfma16(pf0, ones, acc_l);
#pragma unroll
        for (int jd = 0; jd < 4; jd++) {
            bf16x8 vf = *(const bf16x8*)&Vs[i & 1][2048 + (jd * 16 + l16) * 32 + sl];
            acc_o[jd] = mfma16(pf1, vf, acc_o[jd]);
        }
        acc_l = mfma16(pf1, ones, acc_l);
        __builtin_amdgcn_s_setprio(0);

        // exp(i+1) -> Ps (stride-64 swizzled writes; consumed next iter)
#pragma unroll
        for (int j = 0; j < 4; j++) {
            int cb = 2 * j + (l16 >> 3);
#pragma unroll
            for (int r = 0; r < 4; r += 2) {
                float pa = __builtin_amdgcn_exp2f(scn[j][r]);
                float pb = __builtin_amdgcn_exp2f(scn[j][r + 1]);
                unsigned int u = pk2bf(pa, pb);
                int slot = cb ^ ((quad * 2 + (r >> 1)) & 3);
                int a0 = (quad * 4 + r) * 64 + slot * 8 + (l16 & 7);
                Ps[w][a0]      = (unsigned short)u;
                Ps[w][a0 + 64] = (unsigned short)(u >> 16);
            }
        }
    }

    __syncthreads();   // drain V[NT-1] staged at iter NT-2
    // ---- final PV(NT-1) from Vs[(NT-1)&1]; Ps written at loop bottom ----
    {
        bf16x8 pf0 = *(const bf16x8*)&Ps[w][ps0];
        bf16x8 pf1 = *(const bf16x8*)&Ps[w][ps1];
#pragma unroll
        for (int jd = 0; jd < 4; jd++) {
            bf16x8 vf = *(const bf16x8*)&Vs[(NT - 1) & 1][(jd * 16 + l16) * 32 + sl];
            acc_o[jd] = mfma16(pf0, vf, acc_o[jd]);
        }
        acc_l = mfma16(pf0, ones, acc_l);
#pragma unroll
        for (int jd = 0; jd < 4; jd++) {
            bf16x8 vf = *(const bf16x8*)&Vs[(NT - 1) & 1][2048 + (jd * 16 + l16) * 32 + sl];
            acc_o[jd] = mfma16(pf1, vf, acc_o[jd]);
        }
        acc_l = mfma16(pf1, ones, acc_l);
    }

    const int b = bh >> 4, h = bh & 15;
    f32x4 rl;
#pragma unroll
    for (int r = 0; r < 4; r++) rl[r] = 1.0f / acc_l[r];
#pragma unroll
    for (int jd = 0; jd < 4; jd++)
#pragma unroll
        for (int r = 0; r < 4; r++) {
            int qrow = q0 + quad * 4 + r;
            int col = h * 64 + jd * 16 + l16;
            ctx[((size_t)b * S_ + qrow) * E_ + col] = f2bf(acc_o[jd][r] * rl[r]);
        }
}

// ---------------- Kernel 3: output projection (bf16, g2l16, R8-exact) -------
__global__ __launch_bounds__(256, 4) void out_bf(
    const unsigned short* __restrict__ Cx, const unsigned short* __restrict__ Wob,
    const float* __restrict__ bo, float* __restrict__ out)
{
    __shared__ unsigned short As[128 * 32];
    __shared__ unsigned short Bs[64 * 32];
    const int t = threadIdx.x;
    const int w = t >> 6, lane = t & 63, quad = lane >> 4, l16 = lane & 15;
    const int m0 = blockIdx.y * 128, n0 = blockIdx.x * 64;
    const int wr = w * 32;
    const int r4 = t >> 2, c8 = (t & 3) * 8;
    const unsigned short* Ag = Cx  + (size_t)(m0 + r4) * E_ + c8;
    const unsigned short* Bg = Wob + (size_t)(n0 + r4) * E_ + c8;

    f32x4 zero = {0.f, 0.f, 0.f, 0.f};
    f32x4 acc[2][4];
#pragma unroll
    for (int i = 0; i < 2; i++)
#pragma unroll
        for (int j = 0; j < 4; j++) acc[i][j] = zero;

    for (int kt = 0; kt < E_; kt += 32) {
        __syncthreads();
        g2l16(Ag + kt,           &As[t * 8]);
        g2l16(Ag + 64 * E_ + kt, &As[t * 8 + 2048]);
        g2l16(Bg + kt,           &Bs[t * 8]);
        __syncthreads();
        bf16x8 af[2], bfr[4];
#pragma unroll
        for (int i = 0; i < 2; i++)
            af[i] = *(const bf16x8*)&As[(wr + i * 16 + l16) * 32 + quad * 8];
#pragma unroll
        for (int j = 0; j < 4; j++)
            bfr[j] = *(const bf16x8*)&Bs[(j * 16 + l16) * 32 + quad * 8];
#pragma unroll
        for (int i = 0; i < 2; i++)
#pragma unroll
            for (int j = 0; j < 4; j++)
                acc[i][j] = mfma16(af[i], bfr[j], acc[i][j]);
    }

#pragma unroll
    for (int j = 0; j < 4; j++) {
        int n = n0 + j * 16 + l16;
        float bvv = bo[n];
#pragma unroll
        for (int i = 0; i < 2; i++) {
            int mrow = m0 + wr + i * 16 + quad * 4;
#pragma unroll
            for (int r = 0; r < 4; r++)
                out[(size_t)(mrow + r) * E_ + n] = acc[i][j][r] + bvv;
        }
    }
}

// ================= f32 fallback (ws too small for bf16 path) =================
__global__ __launch_bounds__(256, 3) void qkv_rope_f32(
    const float* __restrict__ X,
    const float* __restrict__ Wq, const float* __restrict__ Wk,
    const float* __restrict__ Wv,
    const float* __restrict__ bq, const float* __restrict__ bk,
    const float* __restrict__ bv,
    unsigned short* __restrict__ Qo, unsigned short* __restrict__ Ko,
    unsigned short* __restrict__ Vo)
{
    __shared__ __align__(16) unsigned char lds_raw[128 * 132 * 2];
    unsigned short* As = (unsigned short*)lds_raw;
    unsigned short* Bs = (unsigned short*)(lds_raw + 8192);
    unsigned short* Cs = (unsigned short*)lds_raw;

    const int t = threadIdx.x;
    const int w = t >> 6, lane = t & 63, quad = lane >> 4, l16 = lane & 15;
    const int wr = (w >> 1) * 64, wc = (w & 1) * 64;
    const int n0 = blockIdx.x * 128, m0 = blockIdx.y * 128;
    const int z = blockIdx.z;
    const float* W    = (z == 0) ? Wq : (z == 1) ? Wk : Wv;
    const float* bias = (z == 0) ? bq : (z == 1) ? bk : bv;

    const int r4 = t >> 2, c8 = (t & 3) * 8;
    const int st = r4 * PT + c8;
    const float* Ag = X + (size_t)(m0 + r4) * E_ + c8;
    const float* Bg = W + (size_t)(n0 + r4) * E_ + c8;

    f32x4 zero = {0.f, 0.f, 0.f, 0.f};
    f32x4 acc[4][4];
#pragma unroll
    for (int i = 0; i < 4; i++)
#pragma unroll
        for (int j = 0; j < 4; j++) acc[i][j] = zero;

    for (int kt = 0; kt < E_; kt += 32) {
        bf16x8 a0 = cvt8(Ag + kt);
        bf16x8 a1 = cvt8(Ag + 64 * E_ + kt);
        bf16x8 b0 = cvt8(Bg + kt);
        bf16x8 b1 = cvt8(Bg + 64 * E_ + kt);
        __syncthreads();
        *(bf16x8*)&As[st]           = a0;
        *(bf16x8*)&As[st + 64 * PT] = a1;
        *(bf16x8*)&Bs[st]           = b0;
        *(bf16x8*)&Bs[st + 64 * PT] = b1;
        __syncthreads();
        bf16x8 af[4], bfr[4];
#pragma unroll
        for (int i = 0; i < 4; i++)
            af[i] = *(const bf16x8*)&As[(wr + i * 16 + l16) * PT + quad * 8];
#pragma unroll
        for (int j = 0; j < 4; j++)
            bfr[j] = *(const bf16x8*)&Bs[(wc + j * 16 + l16) * PT + quad * 8];
#pragma unroll
        for (int i = 0; i < 4; i++)
#pragma unroll
            for (int j = 0; j < 4; j++)
                acc[i][j] = mfma16(af[i], bfr[j], acc[i][j]);
    }

    __syncthreads();
    const int seg = quad;
    if (z < 2) {
        const float C = -0.41524101186091903f;
        const float INV2PI = 0.15915494309189535f;
        const float qscale = (z == 0) ? SCLQ : 1.0f;
#pragma unroll
        for (int j = 0; j < 4; j++) {
            int n_local = wc + j * 16 + l16;
            int n = n0 + n_local;
            int d = n & 63, f = d >> 1;
            float inv_rev = exp2f(C * (float)f) * INV2PI;
            float bvv = bias[n];
            float sgn = (d & 1) ? 1.f : -1.f;
#pragma unroll
            for (int i = 0; i < 4; i++) {
                int mb = wr + i * 16 + quad * 4;
#pragma unroll
                for (int r = 0; r < 4; r++) {
                    int m = m0 + mb + r;
                    int s = m & (S_ - 1);
                    float val = acc[i][j][r] + bvv;
                    float oth = __shfl_xor(val, 1);
                    float rev = (float)s * inv_rev;
                    float fr = rev - rintf(rev);
                    float sn = __builtin_amdgcn_sinf(fr);
                    float cs = __builtin_amdgcn_cosf(fr);
                    Cs[(mb + r) * 132 + n_local] =
                        f2bf((val * cs + sgn * oth * sn) * qscale);
                }
            }
        }
        __syncthreads();
        unsigned short* Out = (z == 0) ? Qo : Ko;
        const int btok = m0 >> 11;
        const int half = seg & 1;
#pragma unroll
        for (int it = 0; it < 16; it++) {
            int m_local = it * 8 + w * 2 + (seg >> 1);
            int s = (m0 + m_local) & (S_ - 1);
            int h = (n0 + half * 64) >> 6;
            u16x4 v = *(const u16x4*)&Cs[m_local * 132 + half * 64 + l16 * 4];
            *(u16x4*)&Out[(((size_t)btok * H_ + h) * S_ + s) * D_ + l16 * 4] = v;
        }
    } else {
#pragma unroll
        for (int j = 0; j < 4; j++) {
            int n_local = wc + j * 16 + l16;
            float bvv = bias[n0 + n_local];
#pragma unroll
            for (int i = 0; i < 4; i++) {
                int mb = wr + i * 16 + quad * 4;
#pragma unroll
                for (int r = 0; r < 4; r++)
                    Cs[n_local * 132 + mb + r] = f2bf(acc[i][j][r] + bvv);
            }
        }
        __syncthreads();
        const int btok = m0 >> 11;
        const int s0 = m0 & (S_ - 1);
        const int half = seg & 1;
#pragma unroll
        for (int it = 0; it < 16; it++) {
            int n_local = it * 8 + w * 2 + (seg >> 1);
            int n = n0 + n_local;
            int h = n >> 6, d = n & 63;
            u16x4 v = *(const u16x4*)&Cs[n_local * 132 + half * 64 + l16 * 4];
            *(u16x4*)&Vo[(((size_t)btok * H_ + h) * D_ + d) * S_ + s0 + half * 64 + l16 * 4] = v;
        }
    }
}

__global__ __launch_bounds__(256, 2) void out_f32(
    const unsigned short* __restrict__ Cx, const float* __restrict__ Wo,
    const float* __restrict__ bo, float* __restrict__ out)
{
    __shared__ unsigned short As[128 * PT];
    __shared__ unsigned short Bs[64 * PT];
    const int t = threadIdx.x;
    const int w = t >> 6, lane = t & 63, quad = lane >> 4, l16 = lane & 15;
    const int m0 = blockIdx.y * 128, n0 = blockIdx.x * 64;
    const int wr = w * 32;
    const int r4 = t >> 2, c8 = (t & 3) * 8;
    const int st = r4 * PT + c8;
    const unsigned short* Ag = Cx + (size_t)(m0 + r4) * E_ + c8;
    const float*          Bg = Wo + (size_t)(n0 + (r4 & 63)) * E_ + c8;

    f32x4 zero = {0.f, 0.f, 0.f, 0.f};
    f32x4 acc[2][4];
#pragma unroll
    for (int i = 0; i < 2; i++)
#pragma unroll
        for (int j = 0; j < 4; j++) acc[i][j] = zero;

    for (int kt = 0; kt < E_; kt += 32) {
        bf16x8 a0 = *(const bf16x8*)(Ag + kt);
        bf16x8 a1 = *(const bf16x8*)(Ag + 64 * E_ + kt);
        bf16x8 b0 = cvt8(Bg + kt);
        __syncthreads();
        *(bf16x8*)&As[st]           = a0;
        *(bf16x8*)&As[st + 64 * PT] = a1;
        *(bf16x8*)&Bs[st]           = b0;
        __syncthreads();
        bf16x8 af[2], bfr[4];
#pragma unroll
        for (int i = 0; i < 2; i++)
            af[i] = *(const bf16x8*)&As[(wr + i * 16 + l16) * PT + quad * 8];
#pragma unroll
        for (int j = 0; j < 4; j++)
            bfr[j] = *(const bf16x8*)&Bs[(j * 16 + l16) * PT + quad * 8];
#pragma unroll
        for (int i = 0; i < 2; i++)
#pragma unroll
            for (int j = 0; j < 4; j++)
                acc[i][j] = mfma16(af[i], bfr[j], acc[i][j]);
    }

#pragma unroll
    for (int j = 0; j < 4; j++) {
        int n = n0 + j * 16 + l16;
        float bvv = bo[n];
#pragma unroll
        for (int i = 0; i < 2; i++) {
            int mrow = m0 + wr + i * 16 + quad * 4;
#pragma unroll
            for (int r = 0; r < 4; r++)
                out[(size_t)(mrow + r) * E_ + n] = acc[i][j][r] + bvv;
        }
    }
}

extern "C" void kernel_launch(void* const* d_in, const int* in_sizes, int n_in,
                              void* d_out, int out_size, void* d_ws, size_t ws_size,
                              hipStream_t stream) {
    const float* X  = (const float*)d_in[0];
    const float* Wq = (const float*)d_in[1];
    const float* bq = (const float*)d_in[2];
    const float* Wk = (const float*)d_in[3];
    const float* bk = (const float*)d_in[4];
    const float* Wv = (const float*)d_in[5];
    const float* bv = (const float*)d_in[6];
    const float* Wo = (const float*)d_in[7];
    const float* bo = (const float*)d_in[8];
    float* outp = (float*)d_out;

    const size_t TN = (size_t)B_ * H_ * S_ * D_;
    const size_t need_f32 = 4 * TN * sizeof(unsigned short);
    const size_t need_bf  = 5 * TN * sizeof(unsigned short) + 2 * 65536 * sizeof(float);
    if (ws_size < need_f32) return;

    unsigned short* Qb = (unsigned short*)d_ws;
    unsigned short* Kb = Qb + TN;
    unsigned short* Vb = Kb + TN;

    if (ws_size >= need_bf) {
        unsigned short* Xb = Vb + TN;   // aliased by Cx after qkv (stream-ordered)
        unsigned short* Wb = Xb + TN;
        float* tab = (float*)(Wb + 4 * (size_t)(E_ * E_));
        unsigned short* Cx = Xb;

        cvt_kernel<<<dim3(2048, 6), 256, 0, stream>>>(X, Wq, Wk, Wv, Wo, Xb, Wb, tab);
        qkv_rope_bf<<<dim3(E_ / 128, M_ / 128, 3), 256, 0, stream>>>(
            Xb, Wb, bq, bk, bv, tab, Qb, Kb, Vb);
        attn_direct<<<dim3(S_ / 64, B_ * H_), 256, 0, stream>>>(Qb, Kb, Vb, Cx);
        out_bf<<<dim3(E_ / 64, M_ / 128), 256, 0, stream>>>(
            Cx, Wb + 3 * (size_t)(E_ * E_), bo, outp);
    } else {
        unsigned short* Cx = Vb + TN;
        qkv_rope_f32<<<dim3(E_ / 128, M_ / 128, 3), 256, 0, stream>>>(
            X, Wq, Wk, Wv, bq, bk, bv, Qb, Kb, Vb);
        attn_direct<<<dim3(S_ / 64, B_ * H_), 256, 0, stream>>>(Qb, Kb, Vb, Cx);
        out_f32<<<dim3(E_ / 64, M_ / 128), 256, 0, stream>>>(Cx, Wo, bo, outp);
    }
}

// Round 11
// 189.875 us; speedup vs baseline: 1.0514x; 1.0514x over previous
//
#include <hip/hip_runtime.h>
#include <hip/hip_bf16.h>
#include <math.h>

#define B_ 2
#define S_ 2048
#define E_ 1024
#define H_ 16
#define D_ 64
#define M_ (B_*S_)
#define PT 32

typedef short bf16x8 __attribute__((ext_vector_type(8)));
typedef float f32x4 __attribute__((ext_vector_type(4)));
typedef unsigned short u16x4 __attribute__((ext_vector_type(4)));

#define SCLQ 0.18033688011112042f  // log2(e)/8 folded into Q

__device__ __forceinline__ unsigned short f2bf(float f) {
    unsigned int u = __builtin_bit_cast(unsigned int, f);
    u += 0x7FFFu + ((u >> 16) & 1u);
    return (unsigned short)(u >> 16);
}
__device__ __forceinline__ unsigned int pk2bf(float a, float b) {
    __hip_bfloat162 h = __float22bfloat162_rn(make_float2(a, b));
    unsigned int u;
    __builtin_memcpy(&u, &h, 4);
    return u;
}
__device__ __forceinline__ f32x4 mfma16(bf16x8 a, bf16x8 b, f32x4 c) {
    return __builtin_amdgcn_mfma_f32_16x16x32_bf16(a, b, c, 0, 0, 0);
}
__device__ __forceinline__ bf16x8 cvt8(const float* p) {
    f32x4 lo = *(const f32x4*)p;
    f32x4 hi = *(const f32x4*)(p + 4);
    unsigned int pk[4];
    pk[0] = pk2bf(lo[0], lo[1]);
    pk[1] = pk2bf(lo[2], lo[3]);
    pk[2] = pk2bf(hi[0], hi[1]);
    pk[3] = pk2bf(hi[2], hi[3]);
    bf16x8 r;
    __builtin_memcpy(&r, pk, 16);
    return r;
}
__device__ __forceinline__ void g2l16(const unsigned short* g, unsigned short* l) {
    __builtin_amdgcn_global_load_lds(
        (const __attribute__((address_space(1))) unsigned int*)(const void*)g,
        (__attribute__((address_space(3))) unsigned int*)(void*)l,
        16, 0, 0);
}

// ---------------- Kernel 0: f32->bf16 conversion + RoPE tables --------------
// R11: exact 1D grid (4352 blocks), no dead blocks (old (2048,6) grid had
// 7680 no-op blocks that guard-exited). Work mapping is exact:
//   [0,2048)    : X    (2048*256*8 = 4194304 elems)
//   [2048,4096) : Wq/Wk/Wv/Wo (512 blocks each, 1048576 elems each)
//   [4096,4352) : RoPE tables (256*256 = 65536 entries)
__global__ __launch_bounds__(256) void cvt_kernel(
    const float* __restrict__ X,  const float* __restrict__ Wq,
    const float* __restrict__ Wk, const float* __restrict__ Wv,
    const float* __restrict__ Wo,
    unsigned short* __restrict__ Xb, unsigned short* __restrict__ Wb,
    float* __restrict__ tab)   // [cs 32*2048][sn 32*2048]
{
    const int bid = blockIdx.x;
    const int t = threadIdx.x;
    if (bid < 2048) {
        size_t i = ((size_t)bid * 256 + t) * 8;
        *(bf16x8*)(Xb + i) = cvt8(X + i);
    } else if (bid < 4096) {
        const int wsel = (bid - 2048) >> 9;   // 0..3 -> Wq,Wk,Wv,Wo
        const float* src = (wsel == 0) ? Wq : (wsel == 1) ? Wk
                         : (wsel == 2) ? Wv : Wo;
        size_t i = ((size_t)((bid - 2048) & 511) * 256 + t) * 8;
        *(bf16x8*)(Wb + (size_t)wsel * (E_ * E_) + i) = cvt8(src + i);
    } else {
        unsigned int i = (unsigned int)(bid - 4096) * 256 + t;
        int f = i >> 11, s = i & 2047;
        const float C = -0.41524101186091903f;     // -log2(10000)/32
        const float INV2PI = 0.15915494309189535f;
        float inv_rev = exp2f(C * (float)f) * INV2PI;
        float rev = (float)s * inv_rev;
        float fr = rev - rintf(rev);
        tab[i]         = __builtin_amdgcn_cosf(fr);
        tab[65536 + i] = __builtin_amdgcn_sinf(fr);
    }
}

// ---------------- Kernel 1: QKV proj + RoPE (bf16, g2l16, table trig) -------
// R8-exact (best measured). R6 BK=64 / R9 dbuf / R5 XCD-remap all null or
// negative: staging latency is already covered by 4-block/CU wave overlap
// (guide m99/m100); XCD chunking thrashes L2 with W copies.
__global__ __launch_bounds__(256, 4) void qkv_rope_bf(
    const unsigned short* __restrict__ Xb, const unsigned short* __restrict__ Wb,
    const float* __restrict__ bq, const float* __restrict__ bk,
    const float* __restrict__ bv, const float* __restrict__ tab,
    unsigned short* __restrict__ Qo, unsigned short* __restrict__ Ko,
    unsigned short* __restrict__ Vo)
{
    __shared__ __align__(16) unsigned char lds_raw[128 * 132 * 2];
    unsigned short* As = (unsigned short*)lds_raw;
    unsigned short* Bs = (unsigned short*)(lds_raw + 8192);
    unsigned short* Cs = (unsigned short*)lds_raw;

    const int t = threadIdx.x;
    const int w = t >> 6, lane = t & 63, quad = lane >> 4, l16 = lane & 15;
    const int wr = (w >> 1) * 64, wc = (w & 1) * 64;
    const int n0 = blockIdx.x * 128, m0 = blockIdx.y * 128;
    const int z = blockIdx.z;
    const unsigned short* W = Wb + (size_t)z * (E_ * E_);
    const float* bias = (z == 0) ? bq : (z == 1) ? bk : bv;

    const int r4 = t >> 2, c8 = (t & 3) * 8;
    const unsigned short* Ag = Xb + (size_t)(m0 + r4) * E_ + c8;
    const unsigned short* Bg = W  + (size_t)(n0 + r4) * E_ + c8;

    f32x4 zero = {0.f, 0.f, 0.f, 0.f};
    f32x4 acc[4][4];
#pragma unroll
    for (int i = 0; i < 4; i++)
#pragma unroll
        for (int j = 0; j < 4; j++) acc[i][j] = zero;

    for (int kt = 0; kt < E_; kt += 32) {
        __syncthreads();
        g2l16(Ag + kt,           &As[t * 8]);
        g2l16(Ag + 64 * E_ + kt, &As[t * 8 + 2048]);
        g2l16(Bg + kt,           &Bs[t * 8]);
        g2l16(Bg + 64 * E_ + kt, &Bs[t * 8 + 2048]);
        __syncthreads();
        bf16x8 af[4], bfr[4];
#pragma unroll
        for (int i = 0; i < 4; i++)
            af[i] = *(const bf16x8*)&As[(wr + i * 16 + l16) * 32 + quad * 8];
#pragma unroll
        for (int j = 0; j < 4; j++)
            bfr[j] = *(const bf16x8*)&Bs[(wc + j * 16 + l16) * 32 + quad * 8];
#pragma unroll
        for (int i = 0; i < 4; i++)
#pragma unroll
            for (int j = 0; j < 4; j++)
                acc[i][j] = mfma16(af[i], bfr[j], acc[i][j]);
    }

    __syncthreads();
    const int seg = quad;
    if (z < 2) {
        const float qscale = (z == 0) ? SCLQ : 1.0f;
#pragma unroll
        for (int j = 0; j < 4; j++) {
            int n_local = wc + j * 16 + l16;
            int n = n0 + n_local;
            int d = n & 63, f = d >> 1;
            float bvv = bias[n];
            float sgn = (d & 1) ? 1.f : -1.f;
            const float* ct = tab + f * 2048;
            const float* st_ = tab + 65536 + f * 2048;
#pragma unroll
            for (int i = 0; i < 4; i++) {
                int mb = wr + i * 16 + quad * 4;
                int sb = (m0 + mb) & (S_ - 1);
                f32x4 cs4 = *(const f32x4*)&ct[sb];
                f32x4 sn4 = *(const f32x4*)&st_[sb];
#pragma unroll
                for (int r = 0; r < 4; r++) {
                    float val = acc[i][j][r] + bvv;
                    float oth = __shfl_xor(val, 1);
                    Cs[(mb + r) * 132 + n_local] =
                        f2bf((val * cs4[r] + sgn * oth * sn4[r]) * qscale);
                }
            }
        }
        __syncthreads();
        unsigned short* Out = (z == 0) ? Qo : Ko;
        const int btok = m0 >> 11;
        const int half = seg & 1;
#pragma unroll
        for (int it = 0; it < 16; it++) {
            int m_local = it * 8 + w * 2 + (seg >> 1);
            int s = (m0 + m_local) & (S_ - 1);
            int h = (n0 + half * 64) >> 6;
            u16x4 v = *(const u16x4*)&Cs[m_local * 132 + half * 64 + l16 * 4];
            *(u16x4*)&Out[(((size_t)btok * H_ + h) * S_ + s) * D_ + l16 * 4] = v;
        }
    } else {
#pragma unroll
        for (int j = 0; j < 4; j++) {
            int n_local = wc + j * 16 + l16;
            float bvv = bias[n0 + n_local];
#pragma unroll
            for (int i = 0; i < 4; i++) {
                int mb = wr + i * 16 + quad * 4;
#pragma unroll
                for (int r = 0; r < 4; r++)
                    Cs[n_local * 132 + mb + r] = f2bf(acc[i][j][r] + bvv);
            }
        }
        __syncthreads();
        const int btok = m0 >> 11;
        const int s0 = m0 & (S_ - 1);
        const int half = seg & 1;
#pragma unroll
        for (int it = 0; it < 16; it++) {
            int n_local = it * 8 + w * 2 + (seg >> 1);
            int n = n0 + n_local;
            int h = n >> 6, d = n & 63;
            u16x4 v = *(const u16x4*)&Cs[n_local * 132 + half * 64 + l16 * 4];
            *(u16x4*)&Vo[(((size_t)btok * H_ + h) * D_ + d) * S_ + s0 + half * 64 + l16 * 4] = v;
        }
    }
}

// ---------------- Kernel 2: attention (R3 structure + XCD swizzle) ----------
// Best-measured attn (~56us). Triple-buffered K/V, one barrier/iter:
//   barrier -> stage(i+2) -> pf(i) -> [QK(i+1) || PV(i)] -> exp -> Ps(i+1)
// XCD swizzle keeps each head's 512KB K/V in ONE XCD L2 (FETCH 69.7->12.3MB).
// K/V LDS use the slot-involution swizzle (slot ^= (row>>1)&3): linear LDS
// dest (g2l16 req), pre-permuted GLOBAL source slot, same involution on read.
// Lessons pinned (do NOT revisit):
//   R4/R10: both 1-block/CU (bigger tile) and 4-block/CU (smaller tile)
//     regress — 2 blocks/CU of this 512-thread shape is the optimum.
//   R7: K=16 PV mfma issues at ~K=32 cycles (2x waste); b64 V-reads can't
//     be de-conflicted by a 16B-granule involution.
//   R5: locality is solved (L2-resident K/V); drain is issue-bound.
__global__ __launch_bounds__(512, 2) void attn_direct(
    const unsigned short* __restrict__ Q, const unsigned short* __restrict__ K,
    const unsigned short* __restrict__ Vt, unsigned short* __restrict__ ctx)
{
    __shared__ unsigned short Ks[3][64 * 64];
    __shared__ unsigned short Vs[3][64 * 64];
    __shared__ unsigned short Ps[8][16 * 72];
    const int t = threadIdx.x;
    const int w = t >> 6, lane = t & 63, quad = lane >> 4, l16 = lane & 15;

    // XCD swizzle: grid (16,32) = 512 wgs; chunk = 64 wgs/XCD
    const int wgid = blockIdx.x + (blockIdx.y << 4);
    const int sw = (wgid & 7) * 64 + (wgid >> 3);
    const int bh = sw >> 4;
    const int q0 = (sw & 15) * 128 + w * 16;
    const int NT = S_ / 64;   // 32 k/v tiles

    const unsigned short* Qg = Q + ((size_t)bh * S_ + q0) * D_;
    bf16x8 qf[2];
#pragma unroll
    for (int ks = 0; ks < 2; ks++)
        qf[ks] = *(const bf16x8*)(Qg + (size_t)l16 * 64 + ks * 32 + quad * 8);

    bf16x8 ones;
#pragma unroll
    for (int e = 0; e < 8; e++) ones[e] = (short)0x3F80;

    f32x4 zero = {0.f, 0.f, 0.f, 0.f};
    f32x4 acc_o[4];
    f32x4 acc_l = zero;
#pragma unroll
    for (int j = 0; j < 4; j++) acc_o[j] = zero;

    const int tt = t & 255, ksel = t >> 8;
    const int sr = tt >> 2;
    // pre-swizzled global source slot: (tt&3) ^ ((row>>1)&3), row = tt>>2
    const int sc = ((tt & 3) ^ ((tt >> 3) & 3)) * 8;
    const unsigned short* KgL = K  + (size_t)bh * S_ * D_ + (size_t)sr * 64 + ksel * 32 + sc;
    const unsigned short* VgL = Vt + (size_t)bh * D_ * S_ + (size_t)sr * S_ + ksel * 32 + sc;

    // read-side swizzled slot (units of 8 elems = 16B): constant per lane
    const int sl = (quad ^ ((l16 >> 1) & 3)) * 8;

    // ---- prologue: stage tile0, drain, stage tile1, QK(0), exp, Ps(0) ----
    g2l16(KgL, &Ks[0][t * 8]);
    g2l16(VgL, &Vs[0][t * 8]);
    __syncthreads();
    g2l16(KgL + 4096, &Ks[1][t * 8]);
    g2l16(VgL + 64,   &Vs[1][t * 8]);
    {
        f32x4 sc4[4];
#pragma unroll
        for (int j = 0; j < 4; j++) sc4[j] = zero;
#pragma unroll
        for (int ks = 0; ks < 2; ks++)
#pragma unroll
            for (int j = 0; j < 4; j++) {
                bf16x8 kf = *(const bf16x8*)&Ks[0][ks * 2048 + (j * 16 + l16) * 32 + sl];
                sc4[j] = mfma16(qf[ks], kf, sc4[j]);
            }
#pragma unroll
        for (int j = 0; j < 4; j++)
#pragma unroll
            for (int r = 0; r < 4; r += 2) {
                float pa = __builtin_amdgcn_exp2f(sc4[j][r]);
                float pb = __builtin_amdgcn_exp2f(sc4[j][r + 1]);
                unsigned int u = pk2bf(pa, pb);
                Ps[w][(quad * 4 + r)     * 72 + j * 16 + l16] = (unsigned short)u;
                Ps[w][(quad * 4 + r + 1) * 72 + j * 16 + l16] = (unsigned short)(u >> 16);
            }
    }

    // ---- main pipelined loop: PV(i) + QK(i+1) per iter, one barrier ----
    int bc = 0, bn = 1, bx = 2;   // cur=tile i, next=tile i+1, stage=tile i+2
    for (int i = 0; i < NT - 1; ++i) {
        __syncthreads();          // tile i+1 staged (vm drain); all waves past PV(i-1)
        if (i + 2 < NT) {
            g2l16(KgL + (size_t)(i + 2) * 4096, &Ks[bx][t * 8]);
            g2l16(VgL + (i + 2) * 64,           &Vs[bx][t * 8]);
        }
        // early pf reads for PV(i) (Ps written before the barrier)
        bf16x8 pf0 = *(const bf16x8*)&Ps[w][l16 * 72 + quad * 8];
        bf16x8 pf1 = *(const bf16x8*)&Ps[w][l16 * 72 + 32 + quad * 8];

        __builtin_amdgcn_s_setprio(1);
        // QK(i+1) from Ks[bn]
        f32x4 scn[4];
#pragma unroll
        for (int j = 0; j < 4; j++) scn[j] = zero;
#pragma unroll
        for (int ks = 0; ks < 2; ks++)
#pragma unroll
            for (int j = 0; j < 4; j++) {
                bf16x8 kf = *(const bf16x8*)&Ks[bn][ks * 2048 + (j * 16 + l16) * 32 + sl];
                scn[j] = mfma16(qf[ks], kf, scn[j]);
            }
        // PV(i) from Vs[bc]
#pragma unroll
        for (int jd = 0; jd < 4; jd++) {
            bf16x8 vf = *(const bf16x8*)&Vs[bc][(jd * 16 + l16) * 32 + sl];
            acc_o[jd] = mfma16(pf0, vf, acc_o[jd]);
        }
        acc_l = mfma16(pf0, ones, acc_l);
#pragma unroll
        for (int jd = 0; jd < 4; jd++) {
            bf16x8 vf = *(const bf16x8*)&Vs[bc][2048 + (jd * 16 + l16) * 32 + sl];
            acc_o[jd] = mfma16(pf1, vf, acc_o[jd]);
        }
        acc_l = mfma16(pf1, ones, acc_l);
        __builtin_amdgcn_s_setprio(0);

        // exp(i+1) -> Ps (consumed next iter, after the barrier's lgkm drain)
#pragma unroll
        for (int j = 0; j < 4; j++)
#pragma unroll
            for (int r = 0; r < 4; r += 2) {
                float pa = __builtin_amdgcn_exp2f(scn[j][r]);
                float pb = __builtin_amdgcn_exp2f(scn[j][r + 1]);
                unsigned int u = pk2bf(pa, pb);
                Ps[w][(quad * 4 + r)     * 72 + j * 16 + l16] = (unsigned short)u;
                Ps[w][(quad * 4 + r + 1) * 72 + j * 16 + l16] = (unsigned short)(u >> 16);
            }

        int tb = bc; bc = bn; bn = bx; bx = tb;
    }

    // ---- final PV(NT-1): tile in bc, Ps written at loop bottom (wave-local)
    {
        bf16x8 pf0 = *(const bf16x8*)&Ps[w][l16 * 72 + quad * 8];
        bf16x8 pf1 = *(const bf16x8*)&Ps[w][l16 * 72 + 32 + quad * 8];
#pragma unroll
        for (int jd = 0; jd < 4; jd++) {
            bf16x8 vf = *(const bf16x8*)&Vs[bc][(jd * 16 + l16) * 32 + sl];
            acc_o[jd] = mfma16(pf0, vf, acc_o[jd]);
        }
        acc_l = mfma16(pf0, ones, acc_l);
#pragma unroll
        for (int jd = 0; jd < 4; jd++) {
            bf16x8 vf = *(const bf16x8*)&Vs[bc][2048 + (jd * 16 + l16) * 32 + sl];
            acc_o[jd] = mfma16(pf1, vf, acc_o[jd]);
        }
        acc_l = mfma16(pf1, ones, acc_l);
    }

    const int b = bh >> 4, h = bh & 15;
    f32x4 rl;
#pragma unroll
    for (int r = 0; r < 4; r++) rl[r] = 1.0f / acc_l[r];
#pragma unroll
    for (int jd = 0; jd < 4; jd++)
#pragma unroll
        for (int r = 0; r < 4; r++) {
            int qrow = q0 + quad * 4 + r;
            int col = h * 64 + jd * 16 + l16;
            ctx[((size_t)b * S_ + qrow) * E_ + col] = f2bf(acc_o[jd][r] * rl[r]);
        }
}

// ---------------- Kernel 3: output projection (bf16, g2l16, R8-exact) -------
__global__ __launch_bounds__(256, 4) void out_bf(
    const unsigned short* __restrict__ Cx, const unsigned short* __restrict__ Wob,
    const float* __restrict__ bo, float* __restrict__ out)
{
    __shared__ unsigned short As[128 * 32];
    __shared__ unsigned short Bs[64 * 32];
    const int t = threadIdx.x;
    const int w = t >> 6, lane = t & 63, quad = lane >> 4, l16 = lane & 15;
    const int m0 = blockIdx.y * 128, n0 = blockIdx.x * 64;
    const int wr = w * 32;
    const int r4 = t >> 2, c8 = (t & 3) * 8;
    const unsigned short* Ag = Cx  + (size_t)(m0 + r4) * E_ + c8;
    const unsigned short* Bg = Wob + (size_t)(n0 + r4) * E_ + c8;

    f32x4 zero = {0.f, 0.f, 0.f, 0.f};
    f32x4 acc[2][4];
#pragma unroll
    for (int i = 0; i < 2; i++)
#pragma unroll
        for (int j = 0; j < 4; j++) acc[i][j] = zero;

    for (int kt = 0; kt < E_; kt += 32) {
        __syncthreads();
        g2l16(Ag + kt,           &As[t * 8]);
        g2l16(Ag + 64 * E_ + kt, &As[t * 8 + 2048]);
        g2l16(Bg + kt,           &Bs[t * 8]);
        __syncthreads();
        bf16x8 af[2], bfr[4];
#pragma unroll
        for (int i = 0; i < 2; i++)
            af[i] = *(const bf16x8*)&As[(wr + i * 16 + l16) * 32 + quad * 8];
#pragma unroll
        for (int j = 0; j < 4; j++)
            bfr[j] = *(const bf16x8*)&Bs[(j * 16 + l16) * 32 + quad * 8];
#pragma unroll
        for (int i = 0; i < 2; i++)
#pragma unroll
            for (int j = 0; j < 4; j++)
                acc[i][j] = mfma16(af[i], bfr[j], acc[i][j]);
    }

#pragma unroll
    for (int j = 0; j < 4; j++) {
        int n = n0 + j * 16 + l16;
        float bvv = bo[n];
#pragma unroll
        for (int i = 0; i < 2; i++) {
            int mrow = m0 + wr + i * 16 + quad * 4;
#pragma unroll
            for (int r = 0; r < 4; r++)
                out[(size_t)(mrow + r) * E_ + n] = acc[i][j][r] + bvv;
        }
    }
}

// ================= f32 fallback (ws too small for bf16 path) =================
__global__ __launch_bounds__(256, 3) void qkv_rope_f32(
    const float* __restrict__ X,
    const float* __restrict__ Wq, const float* __restrict__ Wk,
    const float* __restrict__ Wv,
    const float* __restrict__ bq, const float* __restrict__ bk,
    const float* __restrict__ bv,
    unsigned short* __restrict__ Qo, unsigned short* __restrict__ Ko,
    unsigned short* __restrict__ Vo)
{
    __shared__ __align__(16) unsigned char lds_raw[128 * 132 * 2];
    unsigned short* As = (unsigned short*)lds_raw;
    unsigned short* Bs = (unsigned short*)(lds_raw + 8192);
    unsigned short* Cs = (unsigned short*)lds_raw;

    const int t = threadIdx.x;
    const int w = t >> 6, lane = t & 63, quad = lane >> 4, l16 = lane & 15;
    const int wr = (w >> 1) * 64, wc = (w & 1) * 64;
    const int n0 = blockIdx.x * 128, m0 = blockIdx.y * 128;
    const int z = blockIdx.z;
    const float* W    = (z == 0) ? Wq : (z == 1) ? Wk : Wv;
    const float* bias = (z == 0) ? bq : (z == 1) ? bk : bv;

    const int r4 = t >> 2, c8 = (t & 3) * 8;
    const int st = r4 * PT + c8;
    const float* Ag = X + (size_t)(m0 + r4) * E_ + c8;
    const float* Bg = W + (size_t)(n0 + r4) * E_ + c8;

    f32x4 zero = {0.f, 0.f, 0.f, 0.f};
    f32x4 acc[4][4];
#pragma unroll
    for (int i = 0; i < 4; i++)
#pragma unroll
        for (int j = 0; j < 4; j++) acc[i][j] = zero;

    for (int kt = 0; kt < E_; kt += 32) {
        bf16x8 a0 = cvt8(Ag + kt);
        bf16x8 a1 = cvt8(Ag + 64 * E_ + kt);
        bf16x8 b0 = cvt8(Bg + kt);
        bf16x8 b1 = cvt8(Bg + 64 * E_ + kt);
        __syncthreads();
        *(bf16x8*)&As[st]           = a0;
        *(bf16x8*)&As[st + 64 * PT] = a1;
        *(bf16x8*)&Bs[st]           = b0;
        *(bf16x8*)&Bs[st + 64 * PT] = b1;
        __syncthreads();
        bf16x8 af[4], bfr[4];
#pragma unroll
        for (int i = 0; i < 4; i++)
            af[i] = *(const bf16x8*)&As[(wr + i * 16 + l16) * PT + quad * 8];
#pragma unroll
        for (int j = 0; j < 4; j++)
            bfr[j] = *(const bf16x8*)&Bs[(wc + j * 16 + l16) * PT + quad * 8];
#pragma unroll
        for (int i = 0; i < 4; i++)
#pragma unroll
            for (int j = 0; j < 4; j++)
                acc[i][j] = mfma16(af[i], bfr[j], acc[i][j]);
    }

    __syncthreads();
    const int seg = quad;
    if (z < 2) {
        const float C = -0.41524101186091903f;
        const float INV2PI = 0.15915494309189535f;
        const float qscale = (z == 0) ? SCLQ : 1.0f;
#pragma unroll
        for (int j = 0; j < 4; j++) {
            int n_local = wc + j * 16 + l16;
            int n = n0 + n_local;
            int d = n & 63, f = d >> 1;
            float inv_rev = exp2f(C * (float)f) * INV2PI;
            float bvv = bias[n];
            float sgn = (d & 1) ? 1.f : -1.f;
#pragma unroll
            for (int i = 0; i < 4; i++) {
                int mb = wr + i * 16 + quad * 4;
#pragma unroll
                for (int r = 0; r < 4; r++) {
                    int m = m0 + mb + r;
                    int s = m & (S_ - 1);
                    float val = acc[i][j][r] + bvv;
                    float oth = __shfl_xor(val, 1);
                    float rev = (float)s * inv_rev;
                    float fr = rev - rintf(rev);
                    float sn = __builtin_amdgcn_sinf(fr);
                    float cs = __builtin_amdgcn_cosf(fr);
                    Cs[(mb + r) * 132 + n_local] =
                        f2bf((val * cs + sgn * oth * sn) * qscale);
                }
            }
        }
        __syncthreads();
        unsigned short* Out = (z == 0) ? Qo : Ko;
        const int btok = m0 >> 11;
        const int half = seg & 1;
#pragma unroll
        for (int it = 0; it < 16; it++) {
            int m_local = it * 8 + w * 2 + (seg >> 1);
            int s = (m0 + m_local) & (S_ - 1);
            int h = (n0 + half * 64) >> 6;
            u16x4 v = *(const u16x4*)&Cs[m_local * 132 + half * 64 + l16 * 4];
            *(u16x4*)&Out[(((size_t)btok * H_ + h) * S_ + s) * D_ + l16 * 4] = v;
        }
    } else {
#pragma unroll
        for (int j = 0; j < 4; j++) {
            int n_local = wc + j * 16 + l16;
            float bvv = bias[n0 + n_local];
#pragma unroll
            for (int i = 0; i < 4; i++) {
                int mb = wr + i * 16 + quad * 4;
#pragma unroll
                for (int r = 0; r < 4; r++)
                    Cs[n_local * 132 + mb + r] = f2bf(acc[i][j][r] + bvv);
            }
        }
        __syncthreads();
        const int btok = m0 >> 11;
        const int s0 = m0 & (S_ - 1);
        const int half = seg & 1;
#pragma unroll
        for (int it = 0; it < 16; it++) {
            int n_local = it * 8 + w * 2 + (seg >> 1);
            int n = n0 + n_local;
            int h = n >> 6, d = n & 63;
            u16x4 v = *(const u16x4*)&Cs[n_local * 132 + half * 64 + l16 * 4];
            *(u16x4*)&Vo[(((size_t)btok * H_ + h) * D_ + d) * S_ + s0 + half * 64 + l16 * 4] = v;
        }
    }
}

__global__ __launch_bounds__(256, 2) void out_f32(
    const unsigned short* __restrict__ Cx, const float* __restrict__ Wo,
    const float* __restrict__ bo, float* __restrict__ out)
{
    __shared__ unsigned short As[128 * PT];
    __shared__ unsigned short Bs[64 * PT];
    const int t = threadIdx.x;
    const int w = t >> 6, lane = t & 63, quad = lane >> 4, l16 = lane & 15;
    const int m0 = blockIdx.y * 128, n0 = blockIdx.x * 64;
    const int wr = w * 32;
    const int r4 = t >> 2, c8 = (t & 3) * 8;
    const int st = r4 * PT + c8;
    const unsigned short* Ag = Cx + (size_t)(m0 + r4) * E_ + c8;
    const float*          Bg = Wo + (size_t)(n0 + (r4 & 63)) * E_ + c8;

    f32x4 zero = {0.f, 0.f, 0.f, 0.f};
    f32x4 acc[2][4];
#pragma unroll
    for (int i = 0; i < 2; i++)
#pragma unroll
        for (int j = 0; j < 4; j++) acc[i][j] = zero;

    for (int kt = 0; kt < E_; kt += 32) {
        bf16x8 a0 = *(const bf16x8*)(Ag + kt);
        bf16x8 a1 = *(const bf16x8*)(Ag + 64 * E_ + kt);
        bf16x8 b0 = cvt8(Bg + kt);
        __syncthreads();
        *(bf16x8*)&As[st]           = a0;
        *(bf16x8*)&As[st + 64 * PT] = a1;
        *(bf16x8*)&Bs[st]           = b0;
        __syncthreads();
        bf16x8 af[2], bfr[4];
#pragma unroll
        for (int i = 0; i < 2; i++)
            af[i] = *(const bf16x8*)&As[(wr + i * 16 + l16) * PT + quad * 8];
#pragma unroll
        for (int j = 0; j < 4; j++)
            bfr[j] = *(const bf16x8*)&Bs[(j * 16 + l16) * PT + quad * 8];
#pragma unroll
        for (int i = 0; i < 2; i++)
#pragma unroll
            for (int j = 0; j < 4; j++)
                acc[i][j] = mfma16(af[i], bfr[j], acc[i][j]);
    }

#pragma unroll
    for (int j = 0; j < 4; j++) {
        int n = n0 + j * 16 + l16;
        float bvv = bo[n];
#pragma unroll
        for (int i = 0; i < 2; i++) {
            int mrow = m0 + wr + i * 16 + quad * 4;
#pragma unroll
            for (int r = 0; r < 4; r++)
                out[(size_t)(mrow + r) * E_ + n] = acc[i][j][r] + bvv;
        }
    }
}

extern "C" void kernel_launch(void* const* d_in, const int* in_sizes, int n_in,
                              void* d_out, int out_size, void* d_ws, size_t ws_size,
                              hipStream_t stream) {
    const float* X  = (const float*)d_in[0];
    const float* Wq = (const float*)d_in[1];
    const float* bq = (const float*)d_in[2];
    const float* Wk = (const float*)d_in[3];
    const float* bk = (const float*)d_in[4];
    const float* Wv = (const float*)d_in[5];
    const float* bv = (const float*)d_in[6];
    const float* Wo = (const float*)d_in[7];
    const float* bo = (const float*)d_in[8];
    float* outp = (float*)d_out;

    const size_t TN = (size_t)B_ * H_ * S_ * D_;
    const size_t need_f32 = 4 * TN * sizeof(unsigned short);
    const size_t need_bf  = 5 * TN * sizeof(unsigned short) + 2 * 65536 * sizeof(float);
    if (ws_size < need_f32) return;

    unsigned short* Qb = (unsigned short*)d_ws;
    unsigned short* Kb = Qb + TN;
    unsigned short* Vb = Kb + TN;

    if (ws_size >= need_bf) {
        unsigned short* Xb = Vb + TN;   // aliased by Cx after qkv (stream-ordered)
        unsigned short* Wb = Xb + TN;
        float* tab = (float*)(Wb + 4 * (size_t)(E_ * E_));
        unsigned short* Cx = Xb;

        cvt_kernel<<<dim3(4352), 256, 0, stream>>>(X, Wq, Wk, Wv, Wo, Xb, Wb, tab);
        qkv_rope_bf<<<dim3(E_ / 128, M_ / 128, 3), 256, 0, stream>>>(
            Xb, Wb, bq, bk, bv, tab, Qb, Kb, Vb);
        attn_direct<<<dim3(S_ / 128, B_ * H_), 512, 0, stream>>>(Qb, Kb, Vb, Cx);
        out_bf<<<dim3(E_ / 64, M_ / 128), 256, 0, stream>>>(
            Cx, Wb + 3 * (size_t)(E_ * E_), bo, outp);
    } else {
        unsigned short* Cx = Vb + TN;
        qkv_rope_f32<<<dim3(E_ / 128, M_ / 128, 3), 256, 0, stream>>>(
            X, Wq, Wk, Wv, bq, bk, bv, Qb, Kb, Vb);
        attn_direct<<<dim3(S_ / 128, B_ * H_), 512, 0, stream>>>(Qb, Kb, Vb, Cx);
        out_f32<<<dim3(E_ / 64, M_ / 128), 256, 0, stream>>>(Cx, Wo, bo, outp);
    }
}

// Round 12
// 188.354 us; speedup vs baseline: 1.0599x; 1.0081x over previous
//
#include <hip/hip_runtime.h>
#include <hip/hip_bf16.h>
#include <math.h>

#define B_ 2
#define S_ 2048
#define E_ 1024
#define H_ 16
#define D_ 64
#define M_ (B_*S_)
#define PT 32

typedef short bf16x8 __attribute__((ext_vector_type(8)));
typedef float f32x4 __attribute__((ext_vector_type(4)));
typedef unsigned short u16x4 __attribute__((ext_vector_type(4)));

#define SCLQ 0.18033688011112042f  // log2(e)/8 folded into Q

__device__ __forceinline__ unsigned short f2bf(float f) {
    unsigned int u = __builtin_bit_cast(unsigned int, f);
    u += 0x7FFFu + ((u >> 16) & 1u);
    return (unsigned short)(u >> 16);
}
__device__ __forceinline__ unsigned int pk2bf(float a, float b) {
    __hip_bfloat162 h = __float22bfloat162_rn(make_float2(a, b));
    unsigned int u;
    __builtin_memcpy(&u, &h, 4);
    return u;
}
__device__ __forceinline__ f32x4 mfma16(bf16x8 a, bf16x8 b, f32x4 c) {
    return __builtin_amdgcn_mfma_f32_16x16x32_bf16(a, b, c, 0, 0, 0);
}
__device__ __forceinline__ bf16x8 cvt8(const float* p) {
    f32x4 lo = *(const f32x4*)p;
    f32x4 hi = *(const f32x4*)(p + 4);
    unsigned int pk[4];
    pk[0] = pk2bf(lo[0], lo[1]);
    pk[1] = pk2bf(lo[2], lo[3]);
    pk[2] = pk2bf(hi[0], hi[1]);
    pk[3] = pk2bf(hi[2], hi[3]);
    bf16x8 r;
    __builtin_memcpy(&r, pk, 16);
    return r;
}
__device__ __forceinline__ void g2l16(const unsigned short* g, unsigned short* l) {
    __builtin_amdgcn_global_load_lds(
        (const __attribute__((address_space(1))) unsigned int*)(const void*)g,
        (__attribute__((address_space(3))) unsigned int*)(void*)l,
        16, 0, 0);
}

// ---------------- Kernel 0: f32->bf16 conversion + RoPE tables --------------
// Exact 1D grid (4352 blocks), no dead blocks:
//   [0,2048)    : X            [2048,4096) : Wq/Wk/Wv/Wo (512 each)
//   [4096,4352) : RoPE tables (65536 entries)
__global__ __launch_bounds__(256) void cvt_kernel(
    const float* __restrict__ X,  const float* __restrict__ Wq,
    const float* __restrict__ Wk, const float* __restrict__ Wv,
    const float* __restrict__ Wo,
    unsigned short* __restrict__ Xb, unsigned short* __restrict__ Wb,
    float* __restrict__ tab)   // [cs 32*2048][sn 32*2048]
{
    const int bid = blockIdx.x;
    const int t = threadIdx.x;
    if (bid < 2048) {
        size_t i = ((size_t)bid * 256 + t) * 8;
        *(bf16x8*)(Xb + i) = cvt8(X + i);
    } else if (bid < 4096) {
        const int wsel = (bid - 2048) >> 9;   // 0..3 -> Wq,Wk,Wv,Wo
        const float* src = (wsel == 0) ? Wq : (wsel == 1) ? Wk
                         : (wsel == 2) ? Wv : Wo;
        size_t i = ((size_t)((bid - 2048) & 511) * 256 + t) * 8;
        *(bf16x8*)(Wb + (size_t)wsel * (E_ * E_) + i) = cvt8(src + i);
    } else {
        unsigned int i = (unsigned int)(bid - 4096) * 256 + t;
        int f = i >> 11, s = i & 2047;
        const float C = -0.41524101186091903f;     // -log2(10000)/32
        const float INV2PI = 0.15915494309189535f;
        float inv_rev = exp2f(C * (float)f) * INV2PI;
        float rev = (float)s * inv_rev;
        float fr = rev - rintf(rev);
        tab[i]         = __builtin_amdgcn_cosf(fr);
        tab[65536 + i] = __builtin_amdgcn_sinf(fr);
    }
}

// ---------------- Kernel 1: QKV proj + RoPE (bf16, g2l16, table trig) -------
// Best-measured form (R8). Ledger: BK=64 (R6), dbuf-1-barrier (R9), XCD
// chunk remap (R5) all null/negative — staging is hidden by 4-blk/CU wave
// overlap (m99/m100); the residual cost is barrier skew, which only a full
// 8-phase 256^2 template (T2+T3+T4+T5 co-designed) addresses.
__global__ __launch_bounds__(256, 4) void qkv_rope_bf(
    const unsigned short* __restrict__ Xb, const unsigned short* __restrict__ Wb,
    const float* __restrict__ bq, const float* __restrict__ bk,
    const float* __restrict__ bv, const float* __restrict__ tab,
    unsigned short* __restrict__ Qo, unsigned short* __restrict__ Ko,
    unsigned short* __restrict__ Vo)
{
    __shared__ __align__(16) unsigned char lds_raw[128 * 132 * 2];
    unsigned short* As = (unsigned short*)lds_raw;
    unsigned short* Bs = (unsigned short*)(lds_raw + 8192);
    unsigned short* Cs = (unsigned short*)lds_raw;

    const int t = threadIdx.x;
    const int w = t >> 6, lane = t & 63, quad = lane >> 4, l16 = lane & 15;
    const int wr = (w >> 1) * 64, wc = (w & 1) * 64;
    const int n0 = blockIdx.x * 128, m0 = blockIdx.y * 128;
    const int z = blockIdx.z;
    const unsigned short* W = Wb + (size_t)z * (E_ * E_);
    const float* bias = (z == 0) ? bq : (z == 1) ? bk : bv;

    const int r4 = t >> 2, c8 = (t & 3) * 8;
    const unsigned short* Ag = Xb + (size_t)(m0 + r4) * E_ + c8;
    const unsigned short* Bg = W  + (size_t)(n0 + r4) * E_ + c8;

    f32x4 zero = {0.f, 0.f, 0.f, 0.f};
    f32x4 acc[4][4];
#pragma unroll
    for (int i = 0; i < 4; i++)
#pragma unroll
        for (int j = 0; j < 4; j++) acc[i][j] = zero;

    for (int kt = 0; kt < E_; kt += 32) {
        __syncthreads();
        g2l16(Ag + kt,           &As[t * 8]);
        g2l16(Ag + 64 * E_ + kt, &As[t * 8 + 2048]);
        g2l16(Bg + kt,           &Bs[t * 8]);
        g2l16(Bg + 64 * E_ + kt, &Bs[t * 8 + 2048]);
        __syncthreads();
        bf16x8 af[4], bfr[4];
#pragma unroll
        for (int i = 0; i < 4; i++)
            af[i] = *(const bf16x8*)&As[(wr + i * 16 + l16) * 32 + quad * 8];
#pragma unroll
        for (int j = 0; j < 4; j++)
            bfr[j] = *(const bf16x8*)&Bs[(wc + j * 16 + l16) * 32 + quad * 8];
#pragma unroll
        for (int i = 0; i < 4; i++)
#pragma unroll
            for (int j = 0; j < 4; j++)
                acc[i][j] = mfma16(af[i], bfr[j], acc[i][j]);
    }

    __syncthreads();
    const int seg = quad;
    if (z < 2) {
        const float qscale = (z == 0) ? SCLQ : 1.0f;
#pragma unroll
        for (int j = 0; j < 4; j++) {
            int n_local = wc + j * 16 + l16;
            int n = n0 + n_local;
            int d = n & 63, f = d >> 1;
            float bvv = bias[n];
            float sgn = (d & 1) ? 1.f : -1.f;
            const float* ct = tab + f * 2048;
            const float* st_ = tab + 65536 + f * 2048;
#pragma unroll
            for (int i = 0; i < 4; i++) {
                int mb = wr + i * 16 + quad * 4;
                int sb = (m0 + mb) & (S_ - 1);
                f32x4 cs4 = *(const f32x4*)&ct[sb];
                f32x4 sn4 = *(const f32x4*)&st_[sb];
#pragma unroll
                for (int r = 0; r < 4; r++) {
                    float val = acc[i][j][r] + bvv;
                    float oth = __shfl_xor(val, 1);
                    Cs[(mb + r) * 132 + n_local] =
                        f2bf((val * cs4[r] + sgn * oth * sn4[r]) * qscale);
                }
            }
        }
        __syncthreads();
        unsigned short* Out = (z == 0) ? Qo : Ko;
        const int btok = m0 >> 11;
        const int half = seg & 1;
#pragma unroll
        for (int it = 0; it < 16; it++) {
            int m_local = it * 8 + w * 2 + (seg >> 1);
            int s = (m0 + m_local) & (S_ - 1);
            int h = (n0 + half * 64) >> 6;
            u16x4 v = *(const u16x4*)&Cs[m_local * 132 + half * 64 + l16 * 4];
            *(u16x4*)&Out[(((size_t)btok * H_ + h) * S_ + s) * D_ + l16 * 4] = v;
        }
    } else {
#pragma unroll
        for (int j = 0; j < 4; j++) {
            int n_local = wc + j * 16 + l16;
            float bvv = bias[n0 + n_local];
#pragma unroll
            for (int i = 0; i < 4; i++) {
                int mb = wr + i * 16 + quad * 4;
#pragma unroll
                for (int r = 0; r < 4; r++)
                    Cs[n_local * 132 + mb + r] = f2bf(acc[i][j][r] + bvv);
            }
        }
        __syncthreads();
        const int btok = m0 >> 11;
        const int s0 = m0 & (S_ - 1);
        const int half = seg & 1;
#pragma unroll
        for (int it = 0; it < 16; it++) {
            int n_local = it * 8 + w * 2 + (seg >> 1);
            int n = n0 + n_local;
            int h = n >> 6, d = n & 63;
            u16x4 v = *(const u16x4*)&Cs[n_local * 132 + half * 64 + l16 * 4];
            *(u16x4*)&Vo[(((size_t)btok * H_ + h) * D_ + d) * S_ + s0 + half * 64 + l16 * 4] = v;
        }
    }
}

// ---------------- Kernel 2: attention (best measured ~55.3us) ---------------
// Triple-buffered K/V, one barrier/iter:
//   barrier -> stage(i+2) -> pf(i) -> [QK(i+1) || PV(i)] -> exp -> Ps(i+1)
// XCD swizzle keeps each head's 512KB K/V in ONE XCD L2 (FETCH 69.7->12.3MB).
// K/V LDS use the slot-involution swizzle (slot ^= (row>>1)&3): linear LDS
// dest (g2l16 req), pre-permuted GLOBAL source slot, same involution on read.
// Lessons pinned (measured, do NOT revisit):
//   R4/R10: 1-blk/CU and 4-blk/CU variants both regress — 2 blk/CU of this
//     512-thread shape is the optimum; barrier count scales with block count.
//   R7: K=16 PV mfma issues at ~K=32 cycles; b64 V-reads can't be
//     de-conflicted by a 16B-granule involution.
//   R5: K/V is L2-resident; the per-iter drain is issue/skew-bound, so
//     counted-vmcnt alone is null — loads land long before the drain.
__global__ __launch_bounds__(512, 2) void attn_direct(
    const unsigned short* __restrict__ Q, const unsigned short* __restrict__ K,
    const unsigned short* __restrict__ Vt, unsigned short* __restrict__ ctx)
{
    __shared__ unsigned short Ks[3][64 * 64];
    __shared__ unsigned short Vs[3][64 * 64];
    __shared__ unsigned short Ps[8][16 * 72];
    const int t = threadIdx.x;
    const int w = t >> 6, lane = t & 63, quad = lane >> 4, l16 = lane & 15;

    // XCD swizzle: grid (16,32) = 512 wgs; chunk = 64 wgs/XCD
    const int wgid = blockIdx.x + (blockIdx.y << 4);
    const int sw = (wgid & 7) * 64 + (wgid >> 3);
    const int bh = sw >> 4;
    const int q0 = (sw & 15) * 128 + w * 16;
    const int NT = S_ / 64;   // 32 k/v tiles

    const unsigned short* Qg = Q + ((size_t)bh * S_ + q0) * D_;
    bf16x8 qf[2];
#pragma unroll
    for (int ks = 0; ks < 2; ks++)
        qf[ks] = *(const bf16x8*)(Qg + (size_t)l16 * 64 + ks * 32 + quad * 8);

    bf16x8 ones;
#pragma unroll
    for (int e = 0; e < 8; e++) ones[e] = (short)0x3F80;

    f32x4 zero = {0.f, 0.f, 0.f, 0.f};
    f32x4 acc_o[4];
    f32x4 acc_l = zero;
#pragma unroll
    for (int j = 0; j < 4; j++) acc_o[j] = zero;

    const int tt = t & 255, ksel = t >> 8;
    const int sr = tt >> 2;
    // pre-swizzled global source slot: (tt&3) ^ ((row>>1)&3), row = tt>>2
    const int sc = ((tt & 3) ^ ((tt >> 3) & 3)) * 8;
    const unsigned short* KgL = K  + (size_t)bh * S_ * D_ + (size_t)sr * 64 + ksel * 32 + sc;
    const unsigned short* VgL = Vt + (size_t)bh * D_ * S_ + (size_t)sr * S_ + ksel * 32 + sc;

    // read-side swizzled slot (units of 8 elems = 16B): constant per lane
    const int sl = (quad ^ ((l16 >> 1) & 3)) * 8;

    // ---- prologue: stage tile0, drain, stage tile1, QK(0), exp, Ps(0) ----
    g2l16(KgL, &Ks[0][t * 8]);
    g2l16(VgL, &Vs[0][t * 8]);
    __syncthreads();
    g2l16(KgL + 4096, &Ks[1][t * 8]);
    g2l16(VgL + 64,   &Vs[1][t * 8]);
    {
        f32x4 sc4[4];
#pragma unroll
        for (int j = 0; j < 4; j++) sc4[j] = zero;
#pragma unroll
        for (int ks = 0; ks < 2; ks++)
#pragma unroll
            for (int j = 0; j < 4; j++) {
                bf16x8 kf = *(const bf16x8*)&Ks[0][ks * 2048 + (j * 16 + l16) * 32 + sl];
                sc4[j] = mfma16(qf[ks], kf, sc4[j]);
            }
#pragma unroll
        for (int j = 0; j < 4; j++)
#pragma unroll
            for (int r = 0; r < 4; r += 2) {
                float pa = __builtin_amdgcn_exp2f(sc4[j][r]);
                float pb = __builtin_amdgcn_exp2f(sc4[j][r + 1]);
                unsigned int u = pk2bf(pa, pb);
                Ps[w][(quad * 4 + r)     * 72 + j * 16 + l16] = (unsigned short)u;
                Ps[w][(quad * 4 + r + 1) * 72 + j * 16 + l16] = (unsigned short)(u >> 16);
            }
    }

    // ---- main pipelined loop: PV(i) + QK(i+1) per iter, one barrier ----
    int bc = 0, bn = 1, bx = 2;   // cur=tile i, next=tile i+1, stage=tile i+2
    for (int i = 0; i < NT - 1; ++i) {
        __syncthreads();          // tile i+1 staged (vm drain); all waves past PV(i-1)
        if (i + 2 < NT) {
            g2l16(KgL + (size_t)(i + 2) * 4096, &Ks[bx][t * 8]);
            g2l16(VgL + (i + 2) * 64,           &Vs[bx][t * 8]);
        }
        // early pf reads for PV(i) (Ps written before the barrier)
        bf16x8 pf0 = *(const bf16x8*)&Ps[w][l16 * 72 + quad * 8];
        bf16x8 pf1 = *(const bf16x8*)&Ps[w][l16 * 72 + 32 + quad * 8];

        __builtin_amdgcn_s_setprio(1);
        // QK(i+1) from Ks[bn]
        f32x4 scn[4];
#pragma unroll
        for (int j = 0; j < 4; j++) scn[j] = zero;
#pragma unroll
        for (int ks = 0; ks < 2; ks++)
#pragma unroll
            for (int j = 0; j < 4; j++) {
                bf16x8 kf = *(const bf16x8*)&Ks[bn][ks * 2048 + (j * 16 + l16) * 32 + sl];
                scn[j] = mfma16(qf[ks], kf, scn[j]);
            }
        // PV(i) from Vs[bc]
#pragma unroll
        for (int jd = 0; jd < 4; jd++) {
            bf16x8 vf = *(const bf16x8*)&Vs[bc][(jd * 16 + l16) * 32 + sl];
            acc_o[jd] = mfma16(pf0, vf, acc_o[jd]);
        }
        acc_l = mfma16(pf0, ones, acc_l);
#pragma unroll
        for (int jd = 0; jd < 4; jd++) {
            bf16x8 vf = *(const bf16x8*)&Vs[bc][2048 + (jd * 16 + l16) * 32 + sl];
            acc_o[jd] = mfma16(pf1, vf, acc_o[jd]);
        }
        acc_l = mfma16(pf1, ones, acc_l);
        __builtin_amdgcn_s_setprio(0);

        // exp(i+1) -> Ps (consumed next iter, after the barrier's lgkm drain)
#pragma unroll
        for (int j = 0; j < 4; j++)
#pragma unroll
            for (int r = 0; r < 4; r += 2) {
                float pa = __builtin_amdgcn_exp2f(scn[j][r]);
                float pb = __builtin_amdgcn_exp2f(scn[j][r + 1]);
                unsigned int u = pk2bf(pa, pb);
                Ps[w][(quad * 4 + r)     * 72 + j * 16 + l16] = (unsigned short)u;
                Ps[w][(quad * 4 + r + 1) * 72 + j * 16 + l16] = (unsigned short)(u >> 16);
            }

        int tb = bc; bc = bn; bn = bx; bx = tb;
    }

    // ---- final PV(NT-1): tile in bc, Ps written at loop bottom (wave-local)
    {
        bf16x8 pf0 = *(const bf16x8*)&Ps[w][l16 * 72 + quad * 8];
        bf16x8 pf1 = *(const bf16x8*)&Ps[w][l16 * 72 + 32 + quad * 8];
#pragma unroll
        for (int jd = 0; jd < 4; jd++) {
            bf16x8 vf = *(const bf16x8*)&Vs[bc][(jd * 16 + l16) * 32 + sl];
            acc_o[jd] = mfma16(pf0, vf, acc_o[jd]);
        }
        acc_l = mfma16(pf0, ones, acc_l);
#pragma unroll
        for (int jd = 0; jd < 4; jd++) {
            bf16x8 vf = *(const bf16x8*)&Vs[bc][2048 + (jd * 16 + l16) * 32 + sl];
            acc_o[jd] = mfma16(pf1, vf, acc_o[jd]);
        }
        acc_l = mfma16(pf1, ones, acc_l);
    }

    const int b = bh >> 4, h = bh & 15;
    f32x4 rl;
#pragma unroll
    for (int r = 0; r < 4; r++) rl[r] = 1.0f / acc_l[r];
#pragma unroll
    for (int jd = 0; jd < 4; jd++)
#pragma unroll
        for (int r = 0; r < 4; r++) {
            int qrow = q0 + quad * 4 + r;
            int col = h * 64 + jd * 16 + l16;
            ctx[((size_t)b * S_ + qrow) * E_ + col] = f2bf(acc_o[jd][r] * rl[r]);
        }
}

// ---------------- Kernel 3: output projection (bf16, g2l16, best form) ------
__global__ __launch_bounds__(256, 4) void out_bf(
    const unsigned short* __restrict__ Cx, const unsigned short* __restrict__ Wob,
    const float* __restrict__ bo, float* __restrict__ out)
{
    __shared__ unsigned short As[128 * 32];
    __shared__ unsigned short Bs[64 * 32];
    const int t = threadIdx.x;
    const int w = t >> 6, lane = t & 63, quad = lane >> 4, l16 = lane & 15;
    const int m0 = blockIdx.y * 128, n0 = blockIdx.x * 64;
    const int wr = w * 32;
    const int r4 = t >> 2, c8 = (t & 3) * 8;
    const unsigned short* Ag = Cx  + (size_t)(m0 + r4) * E_ + c8;
    const unsigned short* Bg = Wob + (size_t)(n0 + r4) * E_ + c8;

    f32x4 zero = {0.f, 0.f, 0.f, 0.f};
    f32x4 acc[2][4];
#pragma unroll
    for (int i = 0; i < 2; i++)
#pragma unroll
        for (int j = 0; j < 4; j++) acc[i][j] = zero;

    for (int kt = 0; kt < E_; kt += 32) {
        __syncthreads();
        g2l16(Ag + kt,           &As[t * 8]);
        g2l16(Ag + 64 * E_ + kt, &As[t * 8 + 2048]);
        g2l16(Bg + kt,           &Bs[t * 8]);
        __syncthreads();
        bf16x8 af[2], bfr[4];
#pragma unroll
        for (int i = 0; i < 2; i++)
            af[i] = *(const bf16x8*)&As[(wr + i * 16 + l16) * 32 + quad * 8];
#pragma unroll
        for (int j = 0; j < 4; j++)
            bfr[j] = *(const bf16x8*)&Bs[(j * 16 + l16) * 32 + quad * 8];
#pragma unroll
        for (int i = 0; i < 2; i++)
#pragma unroll
            for (int j = 0; j < 4; j++)
                acc[i][j] = mfma16(af[i], bfr[j], acc[i][j]);
    }

#pragma unroll
    for (int j = 0; j < 4; j++) {
        int n = n0 + j * 16 + l16;
        float bvv = bo[n];
#pragma unroll
        for (int i = 0; i < 2; i++) {
            int mrow = m0 + wr + i * 16 + quad * 4;
#pragma unroll
            for (int r = 0; r < 4; r++)
                out[(size_t)(mrow + r) * E_ + n] = acc[i][j][r] + bvv;
        }
    }
}

// ================= f32 fallback (ws too small for bf16 path) =================
__global__ __launch_bounds__(256, 3) void qkv_rope_f32(
    const float* __restrict__ X,
    const float* __restrict__ Wq, const float* __restrict__ Wk,
    const float* __restrict__ Wv,
    const float* __restrict__ bq, const float* __restrict__ bk,
    const float* __restrict__ bv,
    unsigned short* __restrict__ Qo, unsigned short* __restrict__ Ko,
    unsigned short* __restrict__ Vo)
{
    __shared__ __align__(16) unsigned char lds_raw[128 * 132 * 2];
    unsigned short* As = (unsigned short*)lds_raw;
    unsigned short* Bs = (unsigned short*)(lds_raw + 8192);
    unsigned short* Cs = (unsigned short*)lds_raw;

    const int t = threadIdx.x;
    const int w = t >> 6, lane = t & 63, quad = lane >> 4, l16 = lane & 15;
    const int wr = (w >> 1) * 64, wc = (w & 1) * 64;
    const int n0 = blockIdx.x * 128, m0 = blockIdx.y * 128;
    const int z = blockIdx.z;
    const float* W    = (z == 0) ? Wq : (z == 1) ? Wk : Wv;
    const float* bias = (z == 0) ? bq : (z == 1) ? bk : bv;

    const int r4 = t >> 2, c8 = (t & 3) * 8;
    const int st = r4 * PT + c8;
    const float* Ag = X + (size_t)(m0 + r4) * E_ + c8;
    const float* Bg = W + (size_t)(n0 + r4) * E_ + c8;

    f32x4 zero = {0.f, 0.f, 0.f, 0.f};
    f32x4 acc[4][4];
#pragma unroll
    for (int i = 0; i < 4; i++)
#pragma unroll
        for (int j = 0; j < 4; j++) acc[i][j] = zero;

    for (int kt = 0; kt < E_; kt += 32) {
        bf16x8 a0 = cvt8(Ag + kt);
        bf16x8 a1 = cvt8(Ag + 64 * E_ + kt);
        bf16x8 b0 = cvt8(Bg + kt);
        bf16x8 b1 = cvt8(Bg + 64 * E_ + kt);
        __syncthreads();
        *(bf16x8*)&As[st]           = a0;
        *(bf16x8*)&As[st + 64 * PT] = a1;
        *(bf16x8*)&Bs[st]           = b0;
        *(bf16x8*)&Bs[st + 64 * PT] = b1;
        __syncthreads();
        bf16x8 af[4], bfr[4];
#pragma unroll
        for (int i = 0; i < 4; i++)
            af[i] = *(const bf16x8*)&As[(wr + i * 16 + l16) * PT + quad * 8];
#pragma unroll
        for (int j = 0; j < 4; j++)
            bfr[j] = *(const bf16x8*)&Bs[(wc + j * 16 + l16) * PT + quad * 8];
#pragma unroll
        for (int i = 0; i < 4; i++)
#pragma unroll
            for (int j = 0; j < 4; j++)
                acc[i][j] = mfma16(af[i], bfr[j], acc[i][j]);
    }

    __syncthreads();
    const int seg = quad;
    if (z < 2) {
        const float C = -0.41524101186091903f;
        const float INV2PI = 0.15915494309189535f;
        const float qscale = (z == 0) ? SCLQ : 1.0f;
#pragma unroll
        for (int j = 0; j < 4; j++) {
            int n_local = wc + j * 16 + l16;
            int n = n0 + n_local;
            int d = n & 63, f = d >> 1;
            float inv_rev = exp2f(C * (float)f) * INV2PI;
            float bvv = bias[n];
            float sgn = (d & 1) ? 1.f : -1.f;
#pragma unroll
            for (int i = 0; i < 4; i++) {
                int mb = wr + i * 16 + quad * 4;
#pragma unroll
                for (int r = 0; r < 4; r++) {
                    int m = m0 + mb + r;
                    int s = m & (S_ - 1);
                    float val = acc[i][j][r] + bvv;
                    float oth = __shfl_xor(val, 1);
                    float rev = (float)s * inv_rev;
                    float fr = rev - rintf(rev);
                    float sn = __builtin_amdgcn_sinf(fr);
                    float cs = __builtin_amdgcn_cosf(fr);
                    Cs[(mb + r) * 132 + n_local] =
                        f2bf((val * cs + sgn * oth * sn) * qscale);
                }
            }
        }
        __syncthreads();
        unsigned short* Out = (z == 0) ? Qo : Ko;
        const int btok = m0 >> 11;
        const int half = seg & 1;
#pragma unroll
        for (int it = 0; it < 16; it++) {
            int m_local = it * 8 + w * 2 + (seg >> 1);
            int s = (m0 + m_local) & (S_ - 1);
            int h = (n0 + half * 64) >> 6;
            u16x4 v = *(const u16x4*)&Cs[m_local * 132 + half * 64 + l16 * 4];
            *(u16x4*)&Out[(((size_t)btok * H_ + h) * S_ + s) * D_ + l16 * 4] = v;
        }
    } else {
#pragma unroll
        for (int j = 0; j < 4; j++) {
            int n_local = wc + j * 16 + l16;
            float bvv = bias[n0 + n_local];
#pragma unroll
            for (int i = 0; i < 4; i++) {
                int mb = wr + i * 16 + quad * 4;
#pragma unroll
                for (int r = 0; r < 4; r++)
                    Cs[n_local * 132 + mb + r] = f2bf(acc[i][j][r] + bvv);
            }
        }
        __syncthreads();
        const int btok = m0 >> 11;
        const int s0 = m0 & (S_ - 1);
        const int half = seg & 1;
#pragma unroll
        for (int it = 0; it < 16; it++) {
            int n_local = it * 8 + w * 2 + (seg >> 1);
            int n = n0 + n_local;
            int h = n >> 6, d = n & 63;
            u16x4 v = *(const u16x4*)&Cs[n_local * 132 + half * 64 + l16 * 4];
            *(u16x4*)&Vo[(((size_t)btok * H_ + h) * D_ + d) * S_ + s0 + half * 64 + l16 * 4] = v;
        }
    }
}

__global__ __launch_bounds__(256, 2) void out_f32(
    const unsigned short* __restrict__ Cx, const float* __restrict__ Wo,
    const float* __restrict__ bo, float* __restrict__ out)
{
    __shared__ unsigned short As[128 * PT];
    __shared__ unsigned short Bs[64 * PT];
    const int t = threadIdx.x;
    const int w = t >> 6, lane = t & 63, quad = lane >> 4, l16 = lane & 15;
    const int m0 = blockIdx.y * 128, n0 = blockIdx.x * 64;
    const int wr = w * 32;
    const int r4 = t >> 2, c8 = (t & 3) * 8;
    const int st = r4 * PT + c8;
    const unsigned short* Ag = Cx + (size_t)(m0 + r4) * E_ + c8;
    const float*          Bg = Wo + (size_t)(n0 + (r4 & 63)) * E_ + c8;

    f32x4 zero = {0.f, 0.f, 0.f, 0.f};
    f32x4 acc[2][4];
#pragma unroll
    for (int i = 0; i < 2; i++)
#pragma unroll
        for (int j = 0; j < 4; j++) acc[i][j] = zero;

    for (int kt = 0; kt < E_; kt += 32) {
        bf16x8 a0 = *(const bf16x8*)(Ag + kt);
        bf16x8 a1 = *(const bf16x8*)(Ag + 64 * E_ + kt);
        bf16x8 b0 = cvt8(Bg + kt);
        __syncthreads();
        *(bf16x8*)&As[st]           = a0;
        *(bf16x8*)&As[st + 64 * PT] = a1;
        *(bf16x8*)&Bs[st]           = b0;
        __syncthreads();
        bf16x8 af[2], bfr[4];
#pragma unroll
        for (int i = 0; i < 2; i++)
            af[i] = *(const bf16x8*)&As[(wr + i * 16 + l16) * PT + quad * 8];
#pragma unroll
        for (int j = 0; j < 4; j++)
            bfr[j] = *(const bf16x8*)&Bs[(j * 16 + l16) * PT + quad * 8];
#pragma unroll
        for (int i = 0; i < 2; i++)
#pragma unroll
            for (int j = 0; j < 4; j++)
                acc[i][j] = mfma16(af[i], bfr[j], acc[i][j]);
    }

#pragma unroll
    for (int j = 0; j < 4; j++) {
        int n = n0 + j * 16 + l16;
        float bvv = bo[n];
#pragma unroll
        for (int i = 0; i < 2; i++) {
            int mrow = m0 + wr + i * 16 + quad * 4;
#pragma unroll
            for (int r = 0; r < 4; r++)
                out[(size_t)(mrow + r) * E_ + n] = acc[i][j][r] + bvv;
        }
    }
}

extern "C" void kernel_launch(void* const* d_in, const int* in_sizes, int n_in,
                              void* d_out, int out_size, void* d_ws, size_t ws_size,
                              hipStream_t stream) {
    const float* X  = (const float*)d_in[0];
    const float* Wq = (const float*)d_in[1];
    const float* bq = (const float*)d_in[2];
    const float* Wk = (const float*)d_in[3];
    const float* bk = (const float*)d_in[4];
    const float* Wv = (const float*)d_in[5];
    const float* bv = (const float*)d_in[6];
    const float* Wo = (const float*)d_in[7];
    const float* bo = (const float*)d_in[8];
    float* outp = (float*)d_out;

    const size_t TN = (size_t)B_ * H_ * S_ * D_;
    const size_t need_f32 = 4 * TN * sizeof(unsigned short);
    const size_t need_bf  = 5 * TN * sizeof(unsigned short) + 2 * 65536 * sizeof(float);
    if (ws_size < need_f32) return;

    unsigned short* Qb = (unsigned short*)d_ws;
    unsigned short* Kb = Qb + TN;
    unsigned short* Vb = Kb + TN;

    if (ws_size >= need_bf) {
        unsigned short* Xb = Vb + TN;   // aliased by Cx after qkv (stream-ordered)
        unsigned short* Wb = Xb + TN;
        float* tab = (float*)(Wb + 4 * (size_t)(E_ * E_));
        unsigned short* Cx = Xb;

        cvt_kernel<<<dim3(4352), 256, 0, stream>>>(X, Wq, Wk, Wv, Wo, Xb, Wb, tab);
        qkv_rope_bf<<<dim3(E_ / 128, M_ / 128, 3), 256, 0, stream>>>(
            Xb, Wb, bq, bk, bv, tab, Qb, Kb, Vb);
        attn_direct<<<dim3(S_ / 128, B_ * H_), 512, 0, stream>>>(Qb, Kb, Vb, Cx);
        out_bf<<<dim3(E_ / 64, M_ / 128), 256, 0, stream>>>(
            Cx, Wb + 3 * (size_t)(E_ * E_), bo, outp);
    } else {
        unsigned short* Cx = Vb + TN;
        qkv_rope_f32<<<dim3(E_ / 128, M_ / 128, 3), 256, 0, stream>>>(
            X, Wq, Wk, Wv, bq, bk, bv, Qb, Kb, Vb);
        attn_direct<<<dim3(S_ / 128, B_ * H_), 512, 0, stream>>>(Qb, Kb, Vb, Cx);
        out_f32<<<dim3(E_ / 64, M_ / 128), 256, 0, stream>>>(Cx, Wo, bo, outp);
    }
}